// Round 7
// baseline (198.961 us; speedup 1.0000x reference)
//
#include <hip/hip_runtime.h>

#define Bn 8
#define Nn 16384
#define Cn 256
#define NC 32                   // split-K chunks over N (gram); K=512 per (ck)
#define XPB ((size_t)8388608)   // BYTES per batch in packed xp (256*16384*2)
#define HPB ((size_t)4194304)   // halfwords per batch (256*16384)

typedef __attribute__((ext_vector_type(4)))  float f32x4;
typedef __attribute__((ext_vector_type(16))) float f32x16;
typedef __attribute__((ext_vector_type(8)))  _Float16 f16x8;
typedef __attribute__((ext_vector_type(8)))  unsigned short u16x8;

static __device__ __forceinline__ unsigned short f2h(float f) {
    return __builtin_bit_cast(unsigned short, (_Float16)f);
}
static __device__ __forceinline__ f32x16 mfma16h(u16x8 a, u16x8 b, f32x16 c) {
    return __builtin_amdgcn_mfma_f32_32x32x16_f16(
        __builtin_bit_cast(f16x8, a), __builtin_bit_cast(f16x8, b), c, 0, 0, 0);
}

// ---------------- K0 (k_pack): x [C][N] fp32 -> xp fp16 K-tiles + xr fp16 flat + row sums ----
// Block = (b, c16 stripe of 16 rows, nr window of 2048 n). Reads 16 x 8KB sequential streams,
// stages fp16 in LDS, writes 16 tiles x 4KB contiguous + xr flat copy. No atomics/memset.
__global__ __launch_bounds__(256, 2) void k_pack(
    const float* __restrict__ x, unsigned short* __restrict__ xp,
    unsigned short* __restrict__ xr, float* __restrict__ spart) {
  const int blk = blockIdx.x;
  const int nr  = blk & 7;
  const int c16 = (blk >> 3) & 15;
  const int b   = blk >> 7;
  const int t   = threadIdx.x;
  const int rg  = t >> 4;          // row within stripe
  const int sl  = t & 15;
  const int c   = c16 * 16 + rg;

  __shared__ __align__(16) unsigned short lx[16][2048];

  const size_t fbase = (size_t)b * ((size_t)Cn * Nn) + (size_t)c * Nn + nr * 2048;
  const float* src = x + fbase + sl * 4;
  unsigned short* xrd = xr + fbase + sl * 4;   // same flat indexing as x
  float srow = 0.f;
#pragma unroll 8
  for (int i = 0; i < 32; ++i) {
    f32x4 v = *(const f32x4*)(src + i * 64);
    srow += (v.x + v.y) + (v.z + v.w);
    ushort4 h = make_ushort4(f2h(v.x), f2h(v.y), f2h(v.z), f2h(v.w));
    *(ushort4*)(&lx[rg][i * 64 + sl * 4]) = h;
    *(ushort4*)(xrd + i * 64) = h;
  }
  srow += __shfl_xor(srow, 1, 16);
  srow += __shfl_xor(srow, 2, 16);
  srow += __shfl_xor(srow, 4, 16);
  srow += __shfl_xor(srow, 8, 16);
  if (sl == 0) spart[((b * 8 + nr) << 8) + c] = srow;
  __syncthreads();

  // write 16 tiles: thread (wt = t>>4 tile, s = t&15 slot); slot s of row c holds chunk s^(c&15)
  const int wt = t >> 4, s = t & 15;
  char* dst0 = (char*)xp + (size_t)b * XPB + (size_t)(nr * 16 + wt) * 65536 + s * 16;
#pragma unroll
  for (int cr = 0; cr < 16; ++cr) {
    int c2 = c16 * 16 + cr;
    int ch = s ^ cr;                 // (c2 & 15) == cr
    u16x8 v = *(const u16x8*)(&lx[cr][wt * 128 + ch * 8]);
    *(u16x8*)(dst0 + (size_t)c2 * 256) = v;
  }
}

// ---------------- K1 (k_gram): G-partial row-half per block (fp16 MFMA) ----------------
// 512 blocks (b, ck, half) XCD-chunked; 512 thr = 8 waves (2 row x 4 col), acc[2][2].
// K=512 = 4 tiles of 128; verbatim 64KB tile -> LDS; next tile reg-prefetched across compute.
__global__ __launch_bounds__(512, 4) void k_gram(
    const unsigned short* __restrict__ xp, float* __restrict__ gpart) {
  const int swz  = (blockIdx.x & 7) * 64 + (blockIdx.x >> 3);
  const int half = swz & 1;
  const int ck   = (swz >> 1) & 31;
  const int b    = swz >> 6;
  const char* tb0 = (const char*)xp + (size_t)b * XPB + (size_t)(ck * 4) * 65536;

  __shared__ __align__(16) char smem[65536];

  const int t    = threadIdx.x;
  const int lane = t & 63;
  const int w    = t >> 6;
  const int wm = w & 1, wn = w >> 1;     // rows half*128 + wm*64, cols wn*64
  const int ln = lane & 31, kh = lane >> 5;

  f32x16 acc[2][2];
#pragma unroll
  for (int m = 0; m < 2; ++m)
#pragma unroll
    for (int n = 0; n < 2; ++n)
#pragma unroll
      for (int i = 0; i < 16; ++i) acc[m][n][i] = 0.f;

  u16x8 ldreg[8];
#pragma unroll
  for (int r = 0; r < 8; ++r)
    ldreg[r] = *(const u16x8*)(tb0 + (size_t)t * 128 + r * 16);

  for (int kt = 0; kt < 4; ++kt) {
    __syncthreads();                     // readers of previous tile done
#pragma unroll
    for (int r = 0; r < 8; ++r)
      *(u16x8*)(smem + t * 128 + r * 16) = ldreg[r];
    __syncthreads();
    if (kt < 3) {                        // prefetch next tile; in flight across MFMA
#pragma unroll
      for (int r = 0; r < 8; ++r)
        ldreg[r] = *(const u16x8*)(tb0 + (size_t)(kt + 1) * 65536 + (size_t)t * 128 + r * 16);
    }
#pragma unroll
    for (int ch = 0; ch < 8; ++ch) {
      const int cp = ch * 2 + kh;        // 16B k-chunk index
      u16x8 A[2], Bv[2];
#pragma unroll
      for (int m = 0; m < 2; ++m) {
        int r = half * 128 + wm * 64 + m * 32 + ln;
        A[m] = *(const u16x8*)(smem + r * 256 + ((cp ^ (r & 15)) << 4));
      }
#pragma unroll
      for (int n = 0; n < 2; ++n) {
        int r = wn * 64 + n * 32 + ln;
        Bv[n] = *(const u16x8*)(smem + r * 256 + ((cp ^ (r & 15)) << 4));
      }
#pragma unroll
      for (int m = 0; m < 2; ++m)
#pragma unroll
        for (int n = 0; n < 2; ++n)
          acc[m][n] = mfma16h(A[m], Bv[n], acc[m][n]);
    }
  }

  float* gp = gpart + (size_t)(b * NC + ck) * (Cn * Cn);
#pragma unroll
  for (int m = 0; m < 2; ++m)
#pragma unroll
    for (int n = 0; n < 2; ++n)
#pragma unroll
      for (int r2 = 0; r2 < 16; ++r2) {
        int row = half * 128 + wm * 64 + m * 32 + (r2 & 3) + 8 * (r2 >> 2) + 4 * kh;
        int col = wn * 64 + n * 32 + ln;
        gp[row * Cn + col] = acc[m][n][r2];
      }
}

// ---------------- K2 (k_misc, 8 blocks): sv = sum spart; wkT transpose; kN = Wk s + N bk ----
__global__ __launch_bounds__(256) void k_misc(
    const float* __restrict__ spart, const float* __restrict__ wk,
    const float* __restrict__ bk, float* __restrict__ sv,
    float* __restrict__ wkT, float* __restrict__ kN) {
  const int bb = blockIdx.x, t = threadIdx.x;
  __shared__ float s_l[256];
  float a = 0.f;
#pragma unroll
  for (int q = 0; q < 8; ++q) a += spart[((bb * 8 + q) << 8) + t];
  sv[bb * Cn + t] = a;
  s_l[t] = a;
#pragma unroll
  for (int j = 0; j < 32; ++j) {
    int k = bb * 32 + j;
    wkT[k * Cn + t] = wk[t * Cn + k];
  }
  __syncthreads();
  float k2 = 0.f;
  for (int c = 0; c < 256; ++c) k2 += wk[t * Cn + c] * s_l[c];
  kN[bb * Cn + t] = k2 + 16384.f * bk[t];
}

// ---------------- K3 (k_gk): GK = (sum gpart) @ WkT + s*bk^T  (fp32 VALU) ----------------
__global__ __launch_bounds__(256) void k_gk(
    const float* __restrict__ gpart, const float* __restrict__ sv,
    const float* __restrict__ wkT, const float* __restrict__ bk,
    float* __restrict__ GK) {
  const int b = blockIdx.x >> 6, tile = blockIdx.x & 63;
  const int r0 = tile * 4, t = threadIdx.x;
  __shared__ float g_l[4][256];

  float a[4] = {0.f, 0.f, 0.f, 0.f};
  const float* gp = gpart + (size_t)b * NC * 65536 + r0 * 256 + t;
  for (int ck = 0; ck < NC; ++ck) {
#pragma unroll
    for (int j = 0; j < 4; ++j) a[j] += gp[(size_t)ck * 65536 + j * 256];
  }
#pragma unroll
  for (int j = 0; j < 4; ++j) g_l[j][t] = a[j];
  __syncthreads();

  float acc[4] = {0.f, 0.f, 0.f, 0.f};
  for (int k0 = 0; k0 < 256; k0 += 4) {
    float w0 = wkT[(k0 + 0) * 256 + t];
    float w1 = wkT[(k0 + 1) * 256 + t];
    float w2 = wkT[(k0 + 2) * 256 + t];
    float w3 = wkT[(k0 + 3) * 256 + t];
#pragma unroll
    for (int r = 0; r < 4; ++r) {
      f32x4 gv = *(const f32x4*)(&g_l[r][k0]);
      acc[r] += gv.x * w0 + gv.y * w1 + gv.z * w2 + gv.w * w3;
    }
  }
  float bkt = bk[t];
#pragma unroll
  for (int r = 0; r < 4; ++r) {
    float svr = sv[b * 256 + r0 + r];
    GK[((size_t)b * 256 + r0 + r) * 256 + t] = acc[r] + svr * bkt;
  }
}

// ---------------- K4 (k_scores): scores = Wq@GK + bq*kN^T; softmax; ccB(+I) fp16 ----------------
__global__ __launch_bounds__(256) void k_scores(
    const float* __restrict__ wq, const float* __restrict__ GK,
    const float* __restrict__ bq, const float* __restrict__ kN,
    unsigned short* __restrict__ ccB) {
  const int b    = blockIdx.x >> 5;
  const int tile = blockIdx.x & 31;
  const int c0   = tile * 8;
  const int t    = threadIdx.x;

  __shared__ float wq_l[8][256];
  __shared__ float sc_l[8][256];
  __shared__ unsigned short cct_l[256][8];

#pragma unroll
  for (int j = 0; j < 8; ++j) wq_l[j][t] = wq[(c0 + j) * Cn + t];
  __syncthreads();

  float acc[8];
#pragma unroll
  for (int r = 0; r < 8; ++r) acc[r] = 0.f;
  for (int k0 = 0; k0 < 256; k0 += 4) {
    float g0 = GK[((size_t)b * 256 + k0 + 0) * 256 + t];
    float g1 = GK[((size_t)b * 256 + k0 + 1) * 256 + t];
    float g2 = GK[((size_t)b * 256 + k0 + 2) * 256 + t];
    float g3 = GK[((size_t)b * 256 + k0 + 3) * 256 + t];
#pragma unroll
    for (int r = 0; r < 8; ++r) {
      f32x4 qv = *(const f32x4*)(&wq_l[r][k0]);
      acc[r] += qv.x * g0 + qv.y * g1 + qv.z * g2 + qv.w * g3;
    }
  }
  float kNt = kN[b * 256 + t];
#pragma unroll
  for (int r = 0; r < 8; ++r) sc_l[r][t] = acc[r] + bq[c0 + r] * kNt;
  __syncthreads();

  const int r = t >> 5, sub = t & 31;
  float v[8];
#pragma unroll
  for (int j = 0; j < 8; ++j) v[j] = sc_l[r][sub + 32 * j];
  float mx = v[0];
#pragma unroll
  for (int j = 1; j < 8; ++j) mx = fmaxf(mx, v[j]);
#pragma unroll
  for (int msk = 16; msk >= 1; msk >>= 1) mx = fmaxf(mx, __shfl_xor(mx, msk, 32));
  float se = 0.f;
#pragma unroll
  for (int j = 0; j < 8; ++j) { v[j] = __expf(v[j] - mx); se += v[j]; }
#pragma unroll
  for (int msk = 16; msk >= 1; msk >>= 1) se += __shfl_xor(se, msk, 32);
  float inv = 1.f / se;
#pragma unroll
  for (int j = 0; j < 8; ++j) {
    int d = sub + 32 * j;
    float cc = v[j] * inv + ((d == c0 + r) ? 1.f : 0.f);   // fold residual: cc + I
    cct_l[d][r] = f2h(cc);                                 // fp16 now
  }
  __syncthreads();
  *(uint4*)(ccB + (size_t)b * 65536 + (size_t)(tile * 256 + t) * 8) =
      *(const uint4*)(&cct_l[t][0]);
}

// ---------------- K5 (k_out): out = xr_fp16 @ (cc + I), XCD-chunked ----------
__global__ __launch_bounds__(256, 4) void k_out(
    const unsigned short* __restrict__ xr, const unsigned short* __restrict__ ccB,
    float* __restrict__ out) {
  const int swz = (blockIdx.x & 7) * 256 + (blockIdx.x >> 3);
  const int b  = swz >> 8;
  const int n0 = (swz & 255) * 64;
  const unsigned short* xb = xr + (size_t)b * HPB + (size_t)n0 * Cn;
  const unsigned short* cb = ccB + (size_t)b * 65536;
  float* ob = out + (size_t)b * ((size_t)Nn * Cn) + (size_t)n0 * Cn;

  __shared__ __align__(16) char smem[32768];   // [64 rows][512B] fp16, XOR-swizzled

  const int t    = threadIdx.x;
  const int lane = t & 63;
  const int w    = t >> 6;
  const int ln = lane & 31;
  const int kh = lane >> 5;

  f32x16 acc[2][2];
#pragma unroll
  for (int m = 0; m < 2; ++m)
#pragma unroll
    for (int n = 0; n < 2; ++n)
#pragma unroll
      for (int i = 0; i < 16; ++i) acc[m][n][i] = 0.f;

  // stage 64x256 fp16 tile: pure copy, 4KB per instr
#pragma unroll
  for (int i = 0; i < 8; ++i) {
    int fi8 = i * 256 + t;               // 8-halfword group index
    u16x8 v = *(const u16x8*)(xb + (size_t)fi8 * 8);
    int row = fi8 >> 5, g = fi8 & 31;
    *(u16x8*)(smem + row * 512 + ((g << 4) ^ ((row & 31) << 4))) = v;
  }
  __syncthreads();

#pragma unroll
  for (int ks = 0; ks < 16; ++ks) {
    u16x8 A[2], Bv[2];
    const int g = ks * 2 + kh;
#pragma unroll
    for (int m = 0; m < 2; ++m) {
      int row = m * 32 + ln;
      A[m] = *(const u16x8*)(smem + row * 512 + ((g * 16) ^ ((row & 31) << 4)));
    }
#pragma unroll
    for (int n = 0; n < 2; ++n) {
      int d = w * 64 + n * 32 + ln;
      Bv[n] = *(const u16x8*)(cb + (size_t)g * 2048 + (size_t)d * 8);
    }
#pragma unroll
    for (int m = 0; m < 2; ++m)
#pragma unroll
      for (int n = 0; n < 2; ++n)
        acc[m][n] = mfma16h(A[m], Bv[n], acc[m][n]);
  }

#pragma unroll
  for (int m = 0; m < 2; ++m)
#pragma unroll
    for (int n = 0; n < 2; ++n)
#pragma unroll
      for (int r2 = 0; r2 < 16; ++r2) {
        int row = m * 32 + (r2 & 3) + 8 * (r2 >> 2) + 4 * kh;
        int col = w * 64 + n * 32 + ln;
        ob[(size_t)row * Cn + col] = acc[m][n][r2];
      }
}

extern "C" void kernel_launch(void* const* d_in, const int* in_sizes, int n_in,
                              void* d_out, int out_size, void* d_ws, size_t ws_size,
                              hipStream_t stream) {
  const float* x  = (const float*)d_in[0];
  const float* wq = (const float*)d_in[1];
  const float* bq = (const float*)d_in[2];
  const float* wk = (const float*)d_in[3];
  const float* bk = (const float*)d_in[4];
  float* out = (float*)d_out;

  unsigned short* xp = (unsigned short*)d_ws;            // [B] fp16 K-tiles, 67MB
  unsigned short* xr = xp + (size_t)Bn * HPB;            // [B][N][C] fp16 flat, 67MB
  float* gpart = (float*)(xr + (size_t)Bn * HPB);        // [B][NC][256][256] 64MB
  float* spart = gpart + (size_t)Bn * NC * 65536;        // [B][8][256]
  float* sv    = spart + (size_t)Bn * 8 * 256;           // [B][256]
  float* wkT   = sv + (size_t)Bn * 256;                  // [256][256]
  float* kN    = wkT + 65536;                            // [B][256]
  float* GK    = kN + (size_t)Bn * 256;                  // [B][256][256]
  unsigned short* ccB = (unsigned short*)(GK + (size_t)Bn * 65536); // [B][32][256][8] fp16

  hipLaunchKernelGGL(k_pack,   dim3(Bn * 128), dim3(256), 0, stream, x, xp, xr, spart);
  hipLaunchKernelGGL(k_gram,   dim3(Bn * 64),  dim3(512), 0, stream, xp, gpart);
  hipLaunchKernelGGL(k_misc,   dim3(Bn),       dim3(256), 0, stream, spart, wk, bk, sv, wkT, kN);
  hipLaunchKernelGGL(k_gk,     dim3(Bn * 64),  dim3(256), 0, stream, gpart, sv, wkT, bk, GK);
  hipLaunchKernelGGL(k_scores, dim3(Bn * 32),  dim3(256), 0, stream, wq, GK, bq, kN, ccB);
  hipLaunchKernelGGL(k_out,    dim3(Bn * 256), dim3(256), 0, stream, xr, ccB, out);
}

// Round 8
// 180.669 us; speedup vs baseline: 1.1012x; 1.1012x over previous
//
#include <hip/hip_runtime.h>

#define Bn 8
#define Nn 16384
#define Cn 256
#define NC 32                   // split-K chunks over N (gram); K=512 per ck
#define XPB ((size_t)8388608)   // BYTES per batch in packed xp (256*16384*2)
#define HPB ((size_t)4194304)   // halfwords per batch (256*16384)

typedef __attribute__((ext_vector_type(4)))  float f32x4;
typedef __attribute__((ext_vector_type(16))) float f32x16;
typedef __attribute__((ext_vector_type(8)))  _Float16 f16x8;
typedef __attribute__((ext_vector_type(8)))  unsigned short u16x8;

static __device__ __forceinline__ unsigned short f2h(float f) {
    return __builtin_bit_cast(unsigned short, (_Float16)f);
}
static __device__ __forceinline__ f32x16 mfma16h(u16x8 a, u16x8 b, f32x16 c) {
    return __builtin_amdgcn_mfma_f32_32x32x16_f16(
        __builtin_bit_cast(f16x8, a), __builtin_bit_cast(f16x8, b), c, 0, 0, 0);
}

// async global->LDS 16B/lane; g is PER-LANE source, l is wave-uniform LDS dest
static __device__ __forceinline__ void stage16(const void* g, void* l, int lane) {
#if __has_builtin(__builtin_amdgcn_global_load_lds)
  __builtin_amdgcn_global_load_lds(
      (const __attribute__((address_space(1))) void*)g,
      (__attribute__((address_space(3))) void*)l, 16, 0, 0);
#else
  *(u16x8*)((char*)l + lane * 16) = *(const u16x8*)g;
#endif
}

// ---------------- K0 (k_pack): x [C][N] fp32 -> xp fp16 K-tiles + xr fp16 flat + row sums ----
// One row c per block (2048 blocks, no LDS, 8 blocks/CU). Wave wv streams n-window
// [wv*4096, +4096): 2KB contiguous reads, 1KB xr writes, xp tile writes (BK=64 tiles,
// slot = (chunk + (c>>2)) & 7 rotation) in 128B segments.
__global__ __launch_bounds__(256) void k_pack(
    const float* __restrict__ x, unsigned short* __restrict__ xp,
    unsigned short* __restrict__ xr, float* __restrict__ spart) {
  const int blk = blockIdx.x;
  const int c   = blk & 255;
  const int b   = blk >> 8;
  const int t   = threadIdx.x;
  const int wv  = t >> 6;
  const int l   = t & 63;

  const size_t rowbase = (size_t)b * ((size_t)Cn * Nn) + (size_t)c * Nn;
  const float* src = x + rowbase + wv * 4096 + l * 8;
  unsigned short* xrd = xr + rowbase + wv * 4096 + l * 8;
  const int slot = ((l & 7) + (c >> 2)) & 7;                 // chunk = l&7 always
  char* dstb = (char*)xp + (size_t)b * XPB + (size_t)c * 128 + slot * 16;

  float srow = 0.f;
#pragma unroll
  for (int i = 0; i < 8; ++i) {
    f32x4 v0 = *(const f32x4*)(src + i * 512);
    f32x4 v1 = *(const f32x4*)(src + i * 512 + 4);
    srow += (v0.x + v0.y + v0.z + v0.w) + (v1.x + v1.y + v1.z + v1.w);
    u16x8 h;
    h[0] = f2h(v0.x); h[1] = f2h(v0.y); h[2] = f2h(v0.z); h[3] = f2h(v0.w);
    h[4] = f2h(v1.x); h[5] = f2h(v1.y); h[6] = f2h(v1.z); h[7] = f2h(v1.w);
    *(u16x8*)(xrd + i * 512) = h;
    int nt = wv * 64 + i * 8 + (l >> 3);                     // 64-n tile index
    *(u16x8*)(dstb + (size_t)nt * 32768) = h;
  }
  srow += __shfl_xor(srow, 1);
  srow += __shfl_xor(srow, 2);
  srow += __shfl_xor(srow, 4);
  srow += __shfl_xor(srow, 8);
  srow += __shfl_xor(srow, 16);
  srow += __shfl_xor(srow, 32);
  if (l == 0) spart[(((b << 2) + wv) << 8) + c] = srow;
}

// ---------------- K1 (k_gram): G-partial row-half per block (fp16 MFMA) ----------------
// 512 blocks (b, ck, half), XCD-chunked; 256 thr = 4 waves (col groups), acc[4][2]
// (per-wave 128x64 -> 6 ds_read_b128 per 8 MFMA). K=512 = 8 sub-tiles of 64; 2x32KB
// LDS double-buffer, staged async via global_load_lds, one barrier per sub-tile.
__global__ __launch_bounds__(256, 2) void k_gram(
    const unsigned short* __restrict__ xp, float* __restrict__ gpart) {
  const int swz  = (blockIdx.x & 7) * 64 + (blockIdx.x >> 3);
  const int half = swz & 1;
  const int ck   = (swz >> 1) & 31;
  const int b    = swz >> 6;
  const char* tb0 = (const char*)xp + (size_t)b * XPB + (size_t)(ck * 8) * 32768;

  __shared__ __align__(16) char smem[65536];   // 2 x 32KB

  const int t    = threadIdx.x;
  const int lane = t & 63;
  const int w    = t >> 6;        // col group (cols w*64..)
  const int ln = lane & 31, kh = lane >> 5;

  f32x16 acc[4][2];
#pragma unroll
  for (int m = 0; m < 4; ++m)
#pragma unroll
    for (int n = 0; n < 2; ++n)
#pragma unroll
      for (int i = 0; i < 16; ++i) acc[m][n][i] = 0.f;

#pragma unroll
  for (int j = 0; j < 8; ++j)     // prologue: sub-tile 0 -> buf0
    stage16(tb0 + w * 8192 + j * 1024 + lane * 16, smem + w * 8192 + j * 1024, lane);

  for (int st = 0; st < 8; ++st) {
    const char* buf = smem + (st & 1) * 32768;
    __syncthreads();              // drains vmcnt: buf[st&1] ready; other buffer free
    if (st < 7) {
      const char* gsrc = tb0 + (size_t)(st + 1) * 32768;
      char* nbuf = smem + ((st + 1) & 1) * 32768;
#pragma unroll
      for (int j = 0; j < 8; ++j)
        stage16(gsrc + w * 8192 + j * 1024 + lane * 16, nbuf + w * 8192 + j * 1024, lane);
    }
#pragma unroll
    for (int ks = 0; ks < 4; ++ks) {
      const int cp = ks * 2 + kh;                  // 16B k-chunk 0..7
      u16x8 A[4], Bv[2];
#pragma unroll
      for (int m = 0; m < 4; ++m) {
        int r = half * 128 + m * 32 + ln;
        A[m] = *(const u16x8*)(buf + r * 128 + (((cp + (r >> 2)) & 7) << 4));
      }
#pragma unroll
      for (int n = 0; n < 2; ++n) {
        int r = w * 64 + n * 32 + ln;
        Bv[n] = *(const u16x8*)(buf + r * 128 + (((cp + (r >> 2)) & 7) << 4));
      }
#pragma unroll
      for (int m = 0; m < 4; ++m)
#pragma unroll
        for (int n = 0; n < 2; ++n)
          acc[m][n] = mfma16h(A[m], Bv[n], acc[m][n]);
    }
  }

  float* gp = gpart + (size_t)(b * NC + ck) * (Cn * Cn);
#pragma unroll
  for (int m = 0; m < 4; ++m)
#pragma unroll
    for (int n = 0; n < 2; ++n)
#pragma unroll
      for (int r2 = 0; r2 < 16; ++r2) {
        int row = half * 128 + m * 32 + (r2 & 3) + 8 * (r2 >> 2) + 4 * kh;
        int col = w * 64 + n * 32 + ln;
        gp[row * Cn + col] = acc[m][n][r2];
      }
}

// ---------------- K2 (k_misc, 8 blocks): sv = sum spart; wkT transpose; kN = Wk s + N bk ----
__global__ __launch_bounds__(256) void k_misc(
    const float* __restrict__ spart, const float* __restrict__ wk,
    const float* __restrict__ bk, float* __restrict__ sv,
    float* __restrict__ wkT, float* __restrict__ kN) {
  const int bb = blockIdx.x, t = threadIdx.x;
  __shared__ float s_l[256];
  float a = 0.f;
#pragma unroll
  for (int q = 0; q < 4; ++q) a += spart[(((bb << 2) + q) << 8) + t];
  sv[bb * Cn + t] = a;
  s_l[t] = a;
#pragma unroll
  for (int j = 0; j < 32; ++j) {
    int k = bb * 32 + j;
    wkT[k * Cn + t] = wk[t * Cn + k];
  }
  __syncthreads();
  float k2 = 0.f;
  for (int c = 0; c < 256; ++c) k2 += wk[t * Cn + c] * s_l[c];
  kN[bb * Cn + t] = k2 + 16384.f * bk[t];
}

// ---------------- K3 (k_gk): GK = (sum gpart) @ WkT + s*bk^T  (fp32 VALU) ----------------
__global__ __launch_bounds__(256) void k_gk(
    const float* __restrict__ gpart, const float* __restrict__ sv,
    const float* __restrict__ wkT, const float* __restrict__ bk,
    float* __restrict__ GK) {
  const int b = blockIdx.x >> 6, tile = blockIdx.x & 63;
  const int r0 = tile * 4, t = threadIdx.x;
  __shared__ float g_l[4][256];

  float a[4] = {0.f, 0.f, 0.f, 0.f};
  const float* gp = gpart + (size_t)b * NC * 65536 + r0 * 256 + t;
  for (int ck = 0; ck < NC; ++ck) {
#pragma unroll
    for (int j = 0; j < 4; ++j) a[j] += gp[(size_t)ck * 65536 + j * 256];
  }
#pragma unroll
  for (int j = 0; j < 4; ++j) g_l[j][t] = a[j];
  __syncthreads();

  float acc[4] = {0.f, 0.f, 0.f, 0.f};
  for (int k0 = 0; k0 < 256; k0 += 4) {
    float w0 = wkT[(k0 + 0) * 256 + t];
    float w1 = wkT[(k0 + 1) * 256 + t];
    float w2 = wkT[(k0 + 2) * 256 + t];
    float w3 = wkT[(k0 + 3) * 256 + t];
#pragma unroll
    for (int r = 0; r < 4; ++r) {
      f32x4 gv = *(const f32x4*)(&g_l[r][k0]);
      acc[r] += gv.x * w0 + gv.y * w1 + gv.z * w2 + gv.w * w3;
    }
  }
  float bkt = bk[t];
#pragma unroll
  for (int r = 0; r < 4; ++r) {
    float svr = sv[b * 256 + r0 + r];
    GK[((size_t)b * 256 + r0 + r) * 256 + t] = acc[r] + svr * bkt;
  }
}

// ---------------- K4 (k_scores): scores = Wq@GK + bq*kN^T; softmax; ccB(+I) fp16 ----------------
__global__ __launch_bounds__(256) void k_scores(
    const float* __restrict__ wq, const float* __restrict__ GK,
    const float* __restrict__ bq, const float* __restrict__ kN,
    unsigned short* __restrict__ ccB) {
  const int b    = blockIdx.x >> 5;
  const int tile = blockIdx.x & 31;
  const int c0   = tile * 8;
  const int t    = threadIdx.x;

  __shared__ float wq_l[8][256];
  __shared__ float sc_l[8][256];
  __shared__ unsigned short cct_l[256][8];

#pragma unroll
  for (int j = 0; j < 8; ++j) wq_l[j][t] = wq[(c0 + j) * Cn + t];
  __syncthreads();

  float acc[8];
#pragma unroll
  for (int r = 0; r < 8; ++r) acc[r] = 0.f;
  for (int k0 = 0; k0 < 256; k0 += 4) {
    float g0 = GK[((size_t)b * 256 + k0 + 0) * 256 + t];
    float g1 = GK[((size_t)b * 256 + k0 + 1) * 256 + t];
    float g2 = GK[((size_t)b * 256 + k0 + 2) * 256 + t];
    float g3 = GK[((size_t)b * 256 + k0 + 3) * 256 + t];
#pragma unroll
    for (int r = 0; r < 8; ++r) {
      f32x4 qv = *(const f32x4*)(&wq_l[r][k0]);
      acc[r] += qv.x * g0 + qv.y * g1 + qv.z * g2 + qv.w * g3;
    }
  }
  float kNt = kN[b * 256 + t];
#pragma unroll
  for (int r = 0; r < 8; ++r) sc_l[r][t] = acc[r] + bq[c0 + r] * kNt;
  __syncthreads();

  const int r = t >> 5, sub = t & 31;
  float v[8];
#pragma unroll
  for (int j = 0; j < 8; ++j) v[j] = sc_l[r][sub + 32 * j];
  float mx = v[0];
#pragma unroll
  for (int j = 1; j < 8; ++j) mx = fmaxf(mx, v[j]);
#pragma unroll
  for (int msk = 16; msk >= 1; msk >>= 1) mx = fmaxf(mx, __shfl_xor(mx, msk, 32));
  float se = 0.f;
#pragma unroll
  for (int j = 0; j < 8; ++j) { v[j] = __expf(v[j] - mx); se += v[j]; }
#pragma unroll
  for (int msk = 16; msk >= 1; msk >>= 1) se += __shfl_xor(se, msk, 32);
  float inv = 1.f / se;
#pragma unroll
  for (int j = 0; j < 8; ++j) {
    int d = sub + 32 * j;
    float cc = v[j] * inv + ((d == c0 + r) ? 1.f : 0.f);   // fold residual: cc + I
    cct_l[d][r] = f2h(cc);
  }
  __syncthreads();
  *(uint4*)(ccB + (size_t)b * 65536 + (size_t)(tile * 256 + t) * 8) =
      *(const uint4*)(&cct_l[t][0]);
}

// ---------------- K5 (k_out): out = xr_fp16 @ (cc + I), 128-row blocks, XCD-chunked ----------
// Whole 64KB x-tile staged once via global_load_lds with XOR-pre-swizzled SOURCE
// (linear LDS dest, swizzled read -> conflict-free). acc[4][2] per wave, 2 blocks/CU.
__global__ __launch_bounds__(256, 2) void k_out(
    const unsigned short* __restrict__ xr, const unsigned short* __restrict__ ccB,
    float* __restrict__ out) {
  const int swz = (blockIdx.x & 7) * 128 + (blockIdx.x >> 3);
  const int b  = swz >> 7;
  const int n0 = (swz & 127) * 128;
  const unsigned short* xb = xr + (size_t)b * HPB + (size_t)n0 * Cn;
  const unsigned short* cb = ccB + (size_t)b * 65536;
  float* ob = out + (size_t)b * ((size_t)Nn * Cn) + (size_t)n0 * Cn;

  __shared__ __align__(16) char smem[65536];   // [128 rows][512B] fp16

  const int t    = threadIdx.x;
  const int lane = t & 63;
  const int w    = t >> 6;        // col group (d = w*64..)
  const int ln = lane & 31;
  const int kh = lane >> 5;

  f32x16 acc[4][2];
#pragma unroll
  for (int m = 0; m < 4; ++m)
#pragma unroll
    for (int n = 0; n < 2; ++n)
#pragma unroll
      for (int i = 0; i < 16; ++i) acc[m][n][i] = 0.f;

#pragma unroll
  for (int j = 0; j < 16; ++j) {
    int rl = w * 32 + j * 2 + (lane >> 5);
    int sl = lane & 31;
    const char* g = (const char*)(xb + (size_t)rl * 256 + (size_t)((sl ^ (rl & 31)) * 8));
    stage16(g, smem + w * 16384 + j * 1024, lane);
  }
  __syncthreads();

#pragma unroll
  for (int ks = 0; ks < 16; ++ks) {
    const int cp = ks * 2 + kh;                  // 16B k-chunk 0..31
    u16x8 A[4], Bv[2];
#pragma unroll
    for (int m = 0; m < 4; ++m) {
      int r = m * 32 + ln;
      A[m] = *(const u16x8*)(smem + r * 512 + ((cp ^ (r & 31)) << 4));
    }
#pragma unroll
    for (int n = 0; n < 2; ++n) {
      int d = w * 64 + n * 32 + ln;
      Bv[n] = *(const u16x8*)(cb + (size_t)cp * 2048 + (size_t)d * 8);
    }
#pragma unroll
    for (int m = 0; m < 4; ++m)
#pragma unroll
      for (int n = 0; n < 2; ++n)
        acc[m][n] = mfma16h(A[m], Bv[n], acc[m][n]);
  }

#pragma unroll
  for (int m = 0; m < 4; ++m)
#pragma unroll
    for (int n = 0; n < 2; ++n)
#pragma unroll
      for (int r2 = 0; r2 < 16; ++r2) {
        int row = m * 32 + (r2 & 3) + 8 * (r2 >> 2) + 4 * kh;
        int col = w * 64 + n * 32 + ln;
        ob[(size_t)row * Cn + col] = acc[m][n][r2];
      }
}

extern "C" void kernel_launch(void* const* d_in, const int* in_sizes, int n_in,
                              void* d_out, int out_size, void* d_ws, size_t ws_size,
                              hipStream_t stream) {
  const float* x  = (const float*)d_in[0];
  const float* wq = (const float*)d_in[1];
  const float* bq = (const float*)d_in[2];
  const float* wk = (const float*)d_in[3];
  const float* bk = (const float*)d_in[4];
  float* out = (float*)d_out;

  unsigned short* xp = (unsigned short*)d_ws;            // [B] fp16 BK=64 tiles, 64MB
  unsigned short* xr = xp + (size_t)Bn * HPB;            // fp16 flat copy of x, 64MB
  float* gpart = (float*)(xr + (size_t)Bn * HPB);        // [B][NC][256][256] 64MB
  float* spart = gpart + (size_t)Bn * NC * 65536;        // [B][4][256]
  float* sv    = spart + (size_t)Bn * 4 * 256;           // [B][256]
  float* wkT   = sv + (size_t)Bn * 256;                  // [256][256]
  float* kN    = wkT + 65536;                            // [B][256]
  float* GK    = kN + (size_t)Bn * 256;                  // [B][256][256]
  unsigned short* ccB = (unsigned short*)(GK + (size_t)Bn * 65536); // [B][32][256][8] fp16

  hipLaunchKernelGGL(k_pack,   dim3(Bn * 256), dim3(256), 0, stream, x, xp, xr, spart);
  hipLaunchKernelGGL(k_gram,   dim3(Bn * 64),  dim3(256), 0, stream, xp, gpart);
  hipLaunchKernelGGL(k_misc,   dim3(Bn),       dim3(256), 0, stream, spart, wk, bk, sv, wkT, kN);
  hipLaunchKernelGGL(k_gk,     dim3(Bn * 64),  dim3(256), 0, stream, gpart, sv, wkT, bk, GK);
  hipLaunchKernelGGL(k_scores, dim3(Bn * 32),  dim3(256), 0, stream, wq, GK, bq, kN, ccB);
  hipLaunchKernelGGL(k_out,    dim3(Bn * 128), dim3(256), 0, stream, xr, ccB, out);
}

// Round 9
// 135.081 us; speedup vs baseline: 1.4729x; 1.3375x over previous
//
#include <hip/hip_runtime.h>

#define Bn 8
#define Nn 16384
#define Cn 256
#define NC 32                   // split-K chunks over N (gram); K=512 per ck

typedef __attribute__((ext_vector_type(4)))  float f32x4;
typedef __attribute__((ext_vector_type(16))) float f32x16;
typedef __attribute__((ext_vector_type(8)))  _Float16 f16x8;
typedef __attribute__((ext_vector_type(8)))  unsigned short u16x8;

static __device__ __forceinline__ unsigned short f2h(float f) {
    return __builtin_bit_cast(unsigned short, (_Float16)f);
}
static __device__ __forceinline__ f32x16 mfma16h(u16x8 a, u16x8 b, f32x16 c) {
    return __builtin_amdgcn_mfma_f32_32x32x16_f16(
        __builtin_bit_cast(f16x8, a), __builtin_bit_cast(f16x8, b), c, 0, 0, 0);
}

// ---------------- K1 (k_gram): G-partial row-half per block, direct from x ----------------
// 512 blocks (b=XCD, ck, half); 256 thr = 4 waves (col groups), acc[4][2] (wave 128x64).
// Stage BK=64 cols fp32->fp16 into [256 rows][128B] LDS (rotation swizzle, conflict-free),
// double-buffered; 16 loads/thread in flight across compute (T14). Row-sums fused (half 0).
__global__ __launch_bounds__(256, 2) void k_gram(
    const float* __restrict__ x, float* __restrict__ gpart,
    float* __restrict__ spart) {
  const int b    = blockIdx.x & 7;           // 1 batch per XCD
  const int loc  = blockIdx.x >> 3;          // 0..63; halves adjacent in dispatch
  const int ck   = loc >> 1;
  const int half = loc & 1;

  __shared__ __align__(16) char smem[2][32768];   // [256 rows][128B] fp16

  const int t     = threadIdx.x;
  const int lane  = t & 63;
  const int w     = t >> 6;                  // col group (cols w*64..)
  const int ln    = lane & 31, kh = lane >> 5;
  const int rquad = t >> 4;                  // 0..15
  const int c4    = t & 15;                  // 16B column slot within 64-col stage

  const float* xb = x + (size_t)b * ((size_t)Cn * Nn) + (size_t)ck * 512;

  f32x16 acc[4][2];
#pragma unroll
  for (int m = 0; m < 4; ++m)
#pragma unroll
    for (int n = 0; n < 2; ++n)
#pragma unroll
      for (int i = 0; i < 16; ++i) acc[m][n][i] = 0.f;

  float srow[16];
#pragma unroll
  for (int p = 0; p < 16; ++p) srow[p] = 0.f;

  f32x4 ldA[8], ldB[8];
#define LOADA(s) { _Pragma("unroll") for (int p = 0; p < 8; ++p) \
    ldA[p] = *(const f32x4*)(xb + (size_t)(p * 16 + rquad) * Nn + (s) * 64 + c4 * 4); }
#define LOADB(s) { _Pragma("unroll") for (int p = 0; p < 8; ++p) \
    ldB[p] = *(const f32x4*)(xb + (size_t)((p + 8) * 16 + rquad) * Nn + (s) * 64 + c4 * 4); }

  LOADA(0); LOADB(0);

  for (int s = 0; s < 8; ++s) {
    char* buf = smem[s & 1];
    __syncthreads();                          // readers of this buffer done
#pragma unroll
    for (int p = 0; p < 8; ++p) {
      f32x4 v = ldA[p];
      srow[p] += (v.x + v.y) + (v.z + v.w);
      int r = p * 16 + rquad;
      ushort4 hv = make_ushort4(f2h(v.x), f2h(v.y), f2h(v.z), f2h(v.w));
      *(ushort4*)(buf + r * 128 + ((((c4 >> 1) + r) & 7) << 4) + (c4 & 1) * 8) = hv;
    }
#pragma unroll
    for (int p = 0; p < 8; ++p) {
      f32x4 v = ldB[p];
      srow[p + 8] += (v.x + v.y) + (v.z + v.w);
      int r = (p + 8) * 16 + rquad;
      ushort4 hv = make_ushort4(f2h(v.x), f2h(v.y), f2h(v.z), f2h(v.w));
      *(ushort4*)(buf + r * 128 + ((((c4 >> 1) + r) & 7) << 4) + (c4 & 1) * 8) = hv;
    }
    __syncthreads();                          // buffer ready
    if (s < 7) { LOADA(s + 1); LOADB(s + 1); }   // in flight across compute
#pragma unroll
    for (int ks = 0; ks < 4; ++ks) {
      const int cp = ks * 2 + kh;             // 16B k-chunk 0..7
      u16x8 A[4], Bv[2];
#pragma unroll
      for (int m = 0; m < 4; ++m) {
        int r = half * 128 + m * 32 + ln;
        A[m] = *(const u16x8*)(buf + r * 128 + (((cp + r) & 7) << 4));
      }
#pragma unroll
      for (int n = 0; n < 2; ++n) {
        int r = w * 64 + n * 32 + ln;
        Bv[n] = *(const u16x8*)(buf + r * 128 + (((cp + r) & 7) << 4));
      }
#pragma unroll
      for (int m = 0; m < 4; ++m)
#pragma unroll
        for (int n = 0; n < 2; ++n)
          acc[m][n] = mfma16h(A[m], Bv[n], acc[m][n]);
    }
  }
#undef LOADA
#undef LOADB

  if (half == 0) {                            // row sums (each x element loaded once here)
#pragma unroll
    for (int p = 0; p < 16; ++p) {
      float v = srow[p];
      v += __shfl_xor(v, 1);
      v += __shfl_xor(v, 2);
      v += __shfl_xor(v, 4);
      v += __shfl_xor(v, 8);
      if (c4 == 0) spart[(size_t)(b * NC + ck) * Cn + p * 16 + rquad] = v;
    }
  }

  float* gp = gpart + (size_t)(b * NC + ck) * (Cn * Cn);
#pragma unroll
  for (int m = 0; m < 4; ++m)
#pragma unroll
    for (int n = 0; n < 2; ++n)
#pragma unroll
      for (int r2 = 0; r2 < 16; ++r2) {
        int row = half * 128 + m * 32 + (r2 & 3) + 8 * (r2 >> 2) + 4 * kh;
        int col = w * 64 + n * 32 + ln;
        gp[row * Cn + col] = acc[m][n][r2];
      }
}

// ---------------- K2 (k_misc, 8 blocks): sv = sum spart; wkT transpose; kN = Wk s + N bk ----
__global__ __launch_bounds__(256) void k_misc(
    const float* __restrict__ spart, const float* __restrict__ wk,
    const float* __restrict__ bk, float* __restrict__ sv,
    float* __restrict__ wkT, float* __restrict__ kN) {
  const int bb = blockIdx.x, t = threadIdx.x;
  __shared__ float s_l[256];
  float a = 0.f;
#pragma unroll
  for (int q = 0; q < NC; ++q) a += spart[(size_t)(bb * NC + q) * Cn + t];
  sv[bb * Cn + t] = a;
  s_l[t] = a;
#pragma unroll
  for (int j = 0; j < 32; ++j) {
    int k = bb * 32 + j;
    wkT[k * Cn + t] = wk[t * Cn + k];
  }
  __syncthreads();
  float k2 = 0.f;
  for (int c = 0; c < 256; ++c) k2 += wk[t * Cn + c] * s_l[c];
  kN[bb * Cn + t] = k2 + 16384.f * bk[t];
}

// ---------------- K3 (k_gk): GK = (sum gpart) @ WkT + s*bk^T  (fp32 VALU) ----------------
__global__ __launch_bounds__(256) void k_gk(
    const float* __restrict__ gpart, const float* __restrict__ sv,
    const float* __restrict__ wkT, const float* __restrict__ bk,
    float* __restrict__ GK) {
  const int b = blockIdx.x >> 6, tile = blockIdx.x & 63;
  const int r0 = tile * 4, t = threadIdx.x;
  __shared__ float g_l[4][256];

  float a[4] = {0.f, 0.f, 0.f, 0.f};
  const float* gp = gpart + (size_t)b * NC * 65536 + r0 * 256 + t;
  for (int ck = 0; ck < NC; ++ck) {
#pragma unroll
    for (int j = 0; j < 4; ++j) a[j] += gp[(size_t)ck * 65536 + j * 256];
  }
#pragma unroll
  for (int j = 0; j < 4; ++j) g_l[j][t] = a[j];
  __syncthreads();

  float acc[4] = {0.f, 0.f, 0.f, 0.f};
  for (int k0 = 0; k0 < 256; k0 += 4) {
    float w0 = wkT[(k0 + 0) * 256 + t];
    float w1 = wkT[(k0 + 1) * 256 + t];
    float w2 = wkT[(k0 + 2) * 256 + t];
    float w3 = wkT[(k0 + 3) * 256 + t];
#pragma unroll
    for (int r = 0; r < 4; ++r) {
      f32x4 gv = *(const f32x4*)(&g_l[r][k0]);
      acc[r] += gv.x * w0 + gv.y * w1 + gv.z * w2 + gv.w * w3;
    }
  }
  float bkt = bk[t];
#pragma unroll
  for (int r = 0; r < 4; ++r) {
    float svr = sv[b * 256 + r0 + r];
    GK[((size_t)b * 256 + r0 + r) * 256 + t] = acc[r] + svr * bkt;
  }
}

// ---------------- K4 (k_scores): scores = Wq@GK + bq*kN^T; softmax; ccB(+I) fp16 ----------------
__global__ __launch_bounds__(256) void k_scores(
    const float* __restrict__ wq, const float* __restrict__ GK,
    const float* __restrict__ bq, const float* __restrict__ kN,
    unsigned short* __restrict__ ccB) {
  const int b    = blockIdx.x >> 5;
  const int tile = blockIdx.x & 31;
  const int c0   = tile * 8;
  const int t    = threadIdx.x;

  __shared__ float wq_l[8][256];
  __shared__ float sc_l[8][256];
  __shared__ unsigned short cct_l[256][8];

#pragma unroll
  for (int j = 0; j < 8; ++j) wq_l[j][t] = wq[(c0 + j) * Cn + t];
  __syncthreads();

  float acc[8];
#pragma unroll
  for (int r = 0; r < 8; ++r) acc[r] = 0.f;
  for (int k0 = 0; k0 < 256; k0 += 4) {
    float g0 = GK[((size_t)b * 256 + k0 + 0) * 256 + t];
    float g1 = GK[((size_t)b * 256 + k0 + 1) * 256 + t];
    float g2 = GK[((size_t)b * 256 + k0 + 2) * 256 + t];
    float g3 = GK[((size_t)b * 256 + k0 + 3) * 256 + t];
#pragma unroll
    for (int r = 0; r < 8; ++r) {
      f32x4 qv = *(const f32x4*)(&wq_l[r][k0]);
      acc[r] += qv.x * g0 + qv.y * g1 + qv.z * g2 + qv.w * g3;
    }
  }
  float kNt = kN[b * 256 + t];
#pragma unroll
  for (int r = 0; r < 8; ++r) sc_l[r][t] = acc[r] + bq[c0 + r] * kNt;
  __syncthreads();

  const int r = t >> 5, sub = t & 31;
  float v[8];
#pragma unroll
  for (int j = 0; j < 8; ++j) v[j] = sc_l[r][sub + 32 * j];
  float mx = v[0];
#pragma unroll
  for (int j = 1; j < 8; ++j) mx = fmaxf(mx, v[j]);
#pragma unroll
  for (int msk = 16; msk >= 1; msk >>= 1) mx = fmaxf(mx, __shfl_xor(mx, msk, 32));
  float se = 0.f;
#pragma unroll
  for (int j = 0; j < 8; ++j) { v[j] = __expf(v[j] - mx); se += v[j]; }
#pragma unroll
  for (int msk = 16; msk >= 1; msk >>= 1) se += __shfl_xor(se, msk, 32);
  float inv = 1.f / se;
#pragma unroll
  for (int j = 0; j < 8; ++j) {
    int d = sub + 32 * j;
    float cc = v[j] * inv + ((d == c0 + r) ? 1.f : 0.f);   // fold residual: cc + I
    cct_l[d][r] = f2h(cc);
  }
  __syncthreads();
  *(uint4*)(ccB + (size_t)b * 65536 + (size_t)(tile * 256 + t) * 8) =
      *(const uint4*)(&cct_l[t][0]);
}

// ---------------- K5 (k_out): out = x @ (cc + I), direct fp32 x, 128-row blocks ----------
// x-tile read is 128KB fully contiguous ([N][C] view is flat). Stage fp32->fp16 into
// [128][512B] LDS, rotation swizzle (conflict-free). acc[4][2]/wave; ccB fp16 L2-resident.
__global__ __launch_bounds__(256, 2) void k_out(
    const float* __restrict__ x, const unsigned short* __restrict__ ccB,
    float* __restrict__ out) {
  const int b  = blockIdx.x & 7;             // 1 batch per XCD
  const int n0 = (blockIdx.x >> 3) << 7;     // 128-row tiles
  const float* xb = x + (size_t)b * ((size_t)Nn * Cn) + (size_t)n0 * Cn;
  const unsigned short* cb = ccB + (size_t)b * 65536;
  float* ob = out + (size_t)b * ((size_t)Nn * Cn) + (size_t)n0 * Cn;

  __shared__ __align__(16) char smem[65536];  // [128 rows][512B] fp16

  const int t    = threadIdx.x;
  const int lane = t & 63;
  const int w    = t >> 6;                   // col group (d = w*64..)
  const int ln = lane & 31;
  const int kh = lane >> 5;

  f32x16 acc[4][2];
#pragma unroll
  for (int m = 0; m < 4; ++m)
#pragma unroll
    for (int n = 0; n < 2; ++n)
#pragma unroll
      for (int i = 0; i < 16; ++i) acc[m][n][i] = 0.f;

#pragma unroll
  for (int q = 0; q < 4; ++q) {
    f32x4 v[8];
#pragma unroll
    for (int i = 0; i < 8; ++i)
      v[i] = *(const f32x4*)(xb + (size_t)((q * 8 + i) * 256 + t) * 4);
#pragma unroll
    for (int i = 0; i < 8; ++i) {
      int fi = (q * 8 + i) * 256 + t;        // f32x4 index: row = fi>>6, c4 = fi&63
      int r = fi >> 6, c4 = fi & 63;
      ushort4 hv = make_ushort4(f2h(v[i].x), f2h(v[i].y), f2h(v[i].z), f2h(v[i].w));
      *(ushort4*)(smem + r * 512 + ((((c4 >> 1) + r) & 31) << 4) + (c4 & 1) * 8) = hv;
    }
  }
  __syncthreads();

#pragma unroll
  for (int ks = 0; ks < 16; ++ks) {
    const int cp = ks * 2 + kh;              // 16B k-chunk 0..31
    u16x8 A[4], Bv[2];
#pragma unroll
    for (int m = 0; m < 4; ++m) {
      int r = m * 32 + ln;
      A[m] = *(const u16x8*)(smem + r * 512 + (((cp + r) & 31) << 4));
    }
#pragma unroll
    for (int n = 0; n < 2; ++n) {
      int d = w * 64 + n * 32 + ln;
      Bv[n] = *(const u16x8*)(cb + (size_t)cp * 2048 + (size_t)d * 8);
    }
#pragma unroll
    for (int m = 0; m < 4; ++m)
#pragma unroll
      for (int n = 0; n < 2; ++n)
        acc[m][n] = mfma16h(A[m], Bv[n], acc[m][n]);
  }

#pragma unroll
  for (int m = 0; m < 4; ++m)
#pragma unroll
    for (int n = 0; n < 2; ++n)
#pragma unroll
      for (int r2 = 0; r2 < 16; ++r2) {
        int row = m * 32 + (r2 & 3) + 8 * (r2 >> 2) + 4 * kh;
        int col = w * 64 + n * 32 + ln;
        ob[(size_t)row * Cn + col] = acc[m][n][r2];
      }
}

extern "C" void kernel_launch(void* const* d_in, const int* in_sizes, int n_in,
                              void* d_out, int out_size, void* d_ws, size_t ws_size,
                              hipStream_t stream) {
  const float* x  = (const float*)d_in[0];
  const float* wq = (const float*)d_in[1];
  const float* bq = (const float*)d_in[2];
  const float* wk = (const float*)d_in[3];
  const float* bk = (const float*)d_in[4];
  float* out = (float*)d_out;

  float* gpart = (float*)d_ws;                          // [B][NC][256][256] 64MB
  float* spart = gpart + (size_t)Bn * NC * 65536;       // [B][NC][256]
  float* sv    = spart + (size_t)Bn * NC * 256;         // [B][256]
  float* wkT   = sv + (size_t)Bn * 256;                 // [256][256]
  float* kN    = wkT + 65536;                           // [B][256]
  float* GK    = kN + (size_t)Bn * 256;                 // [B][256][256]
  unsigned short* ccB = (unsigned short*)(GK + (size_t)Bn * 65536); // [B][32][256][8] fp16

  hipLaunchKernelGGL(k_gram,   dim3(Bn * NC * 2), dim3(256), 0, stream, x, gpart, spart);
  hipLaunchKernelGGL(k_misc,   dim3(Bn),          dim3(256), 0, stream, spart, wk, bk, sv, wkT, kN);
  hipLaunchKernelGGL(k_gk,     dim3(Bn * 64),     dim3(256), 0, stream, gpart, sv, wkT, bk, GK);
  hipLaunchKernelGGL(k_scores, dim3(Bn * 32),     dim3(256), 0, stream, wq, GK, bq, kN, ccB);
  hipLaunchKernelGGL(k_out,    dim3(Bn * 128),    dim3(256), 0, stream, x, ccB, out);
}